// Round 15
// baseline (1228.051 us; speedup 1.0000x reference)
//
#include <hip/hip_runtime.h>

// HomoMusicGNN: 3-layer mean-SAGE GNN + LN + residual + 1024-way head.
// Round 15: k_agg block 256 -> 1024 threads (16 nodes/block, 1 node/wave):
// 4x fewer block dispatches + more co-resident waves (R2/R9 showed 21%
// occupancy with no static limiter -> dispatch-rate bound). Inner loop and
// per-node math unchanged (bitwise-identical). k_mg = R14 BK=64 (best).

#define kNo 80000
#define kNc 20000
#define kNs 5000
#define kNn 500
#define kNd 50
#define kN  105550
#define kH  256
#define kC  1024
#define kE  605000
#define LN_EPS 1e-5f
#define NBLK 413  // ceil(kN/256)

typedef unsigned int u32;
typedef unsigned short ush;
typedef __attribute__((ext_vector_type(8))) short short8;
typedef __attribute__((ext_vector_type(4))) float f32x4;

__device__ __forceinline__ float b2f(ush b) {
  u32 u = ((u32)b) << 16;
  float f;
  __builtin_memcpy(&f, &u, 4);
  return f;
}
__device__ __forceinline__ ush f2b(float x) {
  u32 u;
  __builtin_memcpy(&u, &x, 4);
  u32 r = (u + 0x7fffu + ((u >> 16) & 1u)) >> 16;
  return (ush)r;
}
__device__ __forceinline__ float up_hi(u32 u) {
  u32 v = u & 0xffff0000u;
  float f;
  __builtin_memcpy(&f, &v, 4);
  return f;
}
__device__ __forceinline__ float up_lo(u32 u) {
  u32 v = u << 16;
  float f;
  __builtin_memcpy(&f, &v, 4);
  return f;
}
__device__ __forceinline__ float upk(u32 u) { return up_hi(u) + up_lo(u); }
__device__ __forceinline__ u32 pk(float x) {
  ush hi = f2b(x);
  ush lo = f2b(x - b2f(hi));
  return (((u32)hi) << 16) | (u32)lo;
}

union S8u {
  u32 w[4];
  short8 s;
};
// 8 packed cols (a=cols k0..k3, b=k4..k7) -> hi short8 + lo short8
__device__ __forceinline__ void unpk8(uint4 a, uint4 b, short8& hi, short8& lo) {
  S8u h, l;
  h.w[0] = (a.x >> 16) | (a.y & 0xffff0000u);
  h.w[1] = (a.z >> 16) | (a.w & 0xffff0000u);
  h.w[2] = (b.x >> 16) | (b.y & 0xffff0000u);
  h.w[3] = (b.z >> 16) | (b.w & 0xffff0000u);
  l.w[0] = (a.x & 0xffffu) | (a.y << 16);
  l.w[1] = (a.z & 0xffffu) | (a.w << 16);
  l.w[2] = (b.x & 0xffffu) | (b.y << 16);
  l.w[3] = (b.z & 0xffffu) | (b.w << 16);
  hi = h.s;
  lo = l.s;
}

__device__ __forceinline__ void gload16(const void* g, void* l) {
  __builtin_amdgcn_global_load_lds((const __attribute__((address_space(1))) u32*)g,
                                   (__attribute__((address_space(3))) u32*)l, 16, 0, 0);
}

struct EdgeTab {
  const int* p[10];
  int n[10], so[10], dofs[10], cum[11];
};

// ---------------- edge flatten + in-degree count ----------------
__global__ __launch_bounds__(256) void k_edges(EdgeTab t, int* __restrict__ src_g,
                                               int* __restrict__ dst_g,
                                               int* __restrict__ cnt) {
  int e = blockIdx.x * 256 + threadIdx.x;
  if (e >= kE) return;
  int s = 0;
#pragma unroll
  for (int i = 1; i < 10; ++i) s += (e >= t.cum[i]) ? 1 : 0;
  int j = e - t.cum[s];
  const int* p = t.p[s];
  int src = p[j] + t.so[s];
  int dst = p[t.n[s] + j] + t.dofs[s];
  src_g[e] = src;
  dst_g[e] = dst;
  atomicAdd(&cnt[dst], 1);
}

// ---------------- last-writer-wins scatter-set (chord feats -> occ) ----------
__global__ __launch_bounds__(256) void k_winner(const int* __restrict__ ei,
                                                int* __restrict__ winner) {
  int e = blockIdx.x * 256 + threadIdx.x;
  if (e >= kNo) return;
  atomicMax(&winner[ei[kNo + e]], e);
}

__global__ __launch_bounds__(256) void k_scat(const int* __restrict__ ei,
                                              const int* __restrict__ winner,
                                              const float* __restrict__ xch,
                                              float* __restrict__ cpo) {
  int tid = blockIdx.x * 256 + threadIdx.x;
  if (tid >= kNo * 8) return;
  int e = tid >> 3, q = tid & 7;
  int d = ei[kNo + e];
  if (winner[d] == e) {
    int s = ei[e];
    ((float4*)cpo)[d * 8 + q] = ((const float4*)xch)[s * 8 + q];
  }
}

// ---------------- input pack: [M][Kp] u32 (hi<<16|lo), zero-padded ----------
__global__ __launch_bounds__(256) void k_pack2(const float* __restrict__ A1, int K1,
                                               const float* __restrict__ A2, int K2,
                                               int Kp, u32* __restrict__ Xp, int M) {
  int tid = blockIdx.x * 256 + threadIdx.x;
  if (tid >= M * Kp) return;
  int r = tid / Kp, c = tid - r * Kp;
  float v = 0.f;
  if (c < K1) v = A1[(size_t)r * K1 + c];
  else if (c < K1 + K2) v = A2[(size_t)r * K2 + (c - K1)];
  Xp[tid] = pk(v);
}

// ---------------- weight split + pad: [256][Kp] hi/lo bf16 ----------------
__global__ __launch_bounds__(256) void k_wsplit(const float* __restrict__ W, int K,
                                                int Kp, ush* __restrict__ hi,
                                                ush* __restrict__ lo) {
  int tid = blockIdx.x * 256 + threadIdx.x;
  if (tid >= 256 * Kp) return;
  int r = tid / Kp, c = tid - r * Kp;
  float v = (c < K) ? W[(size_t)r * K + c] : 0.f;
  ush h = f2b(v);
  hi[tid] = h;
  lo[tid] = f2b(v - b2f(h));
}

// ---------------- MFMA projection: Xp(packed) @ W^T + bias + emb -> h_pk ----
struct PArgs {
  const u32* Xp;     // [M][Kp] packed
  const ush* Wh;     // [256][Kp]
  const ush* Wlo;    // [256][Kp]
  const float* bias; // [256]
  const float* emb;  // [256]
  u32* out;          // h_pk + rowbase*kH
  int M, Kp;
};

__global__ __launch_bounds__(256) void k_pmg(PArgs g) {
  __shared__ u32 Apk[64 * 32];   // 8 KB
  __shared__ ush Wht[256 * 32];  // 16 KB
  __shared__ ush Wlt[256 * 32];  // 16 KB

  const int tid = threadIdx.x;
  const int wv = tid >> 6;
  const int l = tid & 63;
  const int fr = l & 15, fk = l >> 4;
  const int r0 = blockIdx.x * 64;

  const int ac0 = (((fk * 2) ^ (fr & 7)) * 4);
  const int ac1 = (((fk * 2 + 1) ^ (fr & 7)) * 4);
  const int wc8 = ((fk ^ (fr & 3)) * 8);

  const int arow = tid >> 3, ach = tid & 7;
  const int wrow = tid >> 2, wch = tid & 3;
  const int ar0g = (r0 + arow < g.M) ? (r0 + arow) : (g.M - 1);
  const int ar1g = (r0 + arow + 32 < g.M) ? (r0 + arow + 32) : (g.M - 1);
  const int aswz = (ach ^ (arow & 7)) * 4;
  const int wswz = (wch ^ (wrow & 3)) * 8;

  f32x4 acc[4][4];
#pragma unroll
  for (int m = 0; m < 4; ++m)
#pragma unroll
    for (int n = 0; n < 4; ++n) acc[m][n] = (f32x4)(0.f);

  const u32* a0 = g.Xp + (size_t)ar0g * g.Kp + aswz;
  const u32* a1 = g.Xp + (size_t)ar1g * g.Kp + aswz;
  const ush* wh = g.Wh + (size_t)wrow * g.Kp + wswz;
  const ush* wl = g.Wlo + (size_t)wrow * g.Kp + wswz;

#pragma unroll 1
  for (int kc = 0; kc < g.Kp; kc += 32) {
    __syncthreads();
    gload16(a0 + kc, Apk + tid * 4);
    gload16(a1 + kc, Apk + (tid + 256) * 4);
#pragma unroll
    for (int i = 0; i < 4; ++i) {
      gload16(wh + (size_t)i * 64 * g.Kp + kc, Wht + (tid + i * 256) * 8);
      gload16(wl + (size_t)i * 64 * g.Kp + kc, Wlt + (tid + i * 256) * 8);
    }
    __syncthreads();

    short8 ah[4], al[4], whf[4], wlf[4];
#pragma unroll
    for (int m = 0; m < 4; ++m) {
      const uint4 x = *(const uint4*)(Apk + (m * 16 + fr) * 32 + ac0);
      const uint4 y = *(const uint4*)(Apk + (m * 16 + fr) * 32 + ac1);
      unpk8(x, y, ah[m], al[m]);
    }
#pragma unroll
    for (int n = 0; n < 4; ++n) {
      whf[n] = *(const short8*)(Wht + (wv * 64 + n * 16 + fr) * 32 + wc8);
      wlf[n] = *(const short8*)(Wlt + (wv * 64 + n * 16 + fr) * 32 + wc8);
    }
#pragma unroll
    for (int m = 0; m < 4; ++m)
#pragma unroll
      for (int n = 0; n < 4; ++n) {
        acc[m][n] = __builtin_amdgcn_mfma_f32_16x16x32_bf16(ah[m], whf[n],
                                                            acc[m][n], 0, 0, 0);
        acc[m][n] = __builtin_amdgcn_mfma_f32_16x16x32_bf16(ah[m], wlf[n],
                                                            acc[m][n], 0, 0, 0);
        acc[m][n] = __builtin_amdgcn_mfma_f32_16x16x32_bf16(al[m], whf[n],
                                                            acc[m][n], 0, 0, 0);
      }
  }

  float bn[4];
#pragma unroll
  for (int n = 0; n < 4; ++n) {
    const int col = wv * 64 + n * 16 + fr;
    bn[n] = g.bias[col] + g.emb[col];
  }
#pragma unroll
  for (int m = 0; m < 4; ++m)
#pragma unroll
    for (int j = 0; j < 4; ++j) {
      const int ri = r0 + m * 16 + fk * 4 + j;
      if (ri < g.M) {
        u32* op = g.out + (size_t)ri * kH + wv * 64 + fr;
#pragma unroll
        for (int n = 0; n < 4; ++n) op[n * 16] = pk(acc[m][n][j] + bn[n]);
      }
    }
}

// ---------------- CSR build ----------------
__global__ __launch_bounds__(256) void k_scan1(const int* __restrict__ cnt,
                                               int* __restrict__ bsum) {
  __shared__ int s[256];
  int b = blockIdx.x, t = threadIdx.x;
  int i = b * 256 + t;
  s[t] = (i < kN) ? cnt[i] : 0;
  __syncthreads();
  for (int off = 128; off; off >>= 1) {
    if (t < off) s[t] += s[t + off];
    __syncthreads();
  }
  if (t == 0) bsum[b] = s[0];
}

__global__ __launch_bounds__(512) void k_scan2(const int* __restrict__ bsum,
                                               int* __restrict__ bscan) {
  __shared__ int s[512];
  int t = threadIdx.x;
  s[t] = (t < NBLK) ? bsum[t] : 0;
  __syncthreads();
  for (int off = 1; off < 512; off <<= 1) {
    int v = (t >= off) ? s[t - off] : 0;
    __syncthreads();
    s[t] += v;
    __syncthreads();
  }
  if (t < NBLK) bscan[t] = s[t];
}

__global__ __launch_bounds__(256) void k_scan3(const int* __restrict__ cnt,
                                               const int* __restrict__ bscan,
                                               int* __restrict__ rowptr,
                                               int* __restrict__ cursor,
                                               float* __restrict__ inv) {
  __shared__ int s[256];
  int b = blockIdx.x, t = threadIdx.x;
  int i = b * 256 + t;
  int v = (i < kN) ? cnt[i] : 0;
  s[t] = v;
  __syncthreads();
  for (int off = 1; off < 256; off <<= 1) {
    int u = (t >= off) ? s[t - off] : 0;
    __syncthreads();
    s[t] += u;
    __syncthreads();
  }
  int incl = s[t];
  int base = (b > 0) ? bscan[b - 1] : 0;
  int excl = base + incl - v;
  if (i < kN) {
    rowptr[i] = excl;
    cursor[i] = excl;
    inv[i] = 1.f / (float)(v > 1 ? v : 1);
    if (i == kN - 1) rowptr[kN] = excl + v;
  }
}

__global__ __launch_bounds__(256) void k_fill(const int* __restrict__ src_g,
                                              const int* __restrict__ dst_g,
                                              int* __restrict__ cursor,
                                              int* __restrict__ csr_src) {
  int e = blockIdx.x * 256 + threadIdx.x;
  if (e >= kE) return;
  int d = dst_g[e];
  int slot = atomicAdd(&cursor[d], 1);
  csr_src[slot] = src_g[e];
}

// ------- pull-mode mean aggregation: 1 node/wave, 16 waves/block ------------
// Block = 1024 threads (16 nodes): 4x fewer dispatch events, more resident
// waves/CU. Branch-free clamped batch-of-8 gathers (R10-proven inner loop).
// Node order reversed so high-degree tail nodes launch first.
__global__ __launch_bounds__(1024) void k_agg(const u32* __restrict__ hpk,
                                              const int* __restrict__ rowptr,
                                              const int* __restrict__ csr_src,
                                              const float* __restrict__ inv,
                                              u32* __restrict__ apk) {
  const int wave = threadIdx.x >> 6, lane = threadIdx.x & 63;
  const int node = kN - 1 - (blockIdx.x * 16 + wave);
  if (node < 0) return;
  const int jb = rowptr[node], je = rowptr[node + 1];
  float a0 = 0.f, a1 = 0.f, a2 = 0.f, a3 = 0.f;
  const int coff = lane * 4;  // u32 col offset (16B/lane)

  int j = jb;
  while (j < je) {
    const int batch = min(je - j, 64);
    const int myi = csr_src[j + ((lane < batch) ? lane : (batch - 1))];
#pragma unroll 1
    for (int t0 = 0; t0 < batch; t0 += 8) {
      int s[8];
#pragma unroll
      for (int q = 0; q < 8; ++q) {
        const int tt = t0 + q;
        s[q] = __shfl(myi, (tt < batch) ? tt : 0);
      }
      uint4 v[8];
#pragma unroll
      for (int q = 0; q < 8; ++q)
        v[q] = *(const uint4*)(hpk + (size_t)s[q] * kH + coff);
#pragma unroll
      for (int q = 0; q < 8; ++q) {
        const bool ok = (t0 + q) < batch;  // wave-uniform, branch-free select
        a0 += ok ? upk(v[q].x) : 0.f;
        a1 += ok ? upk(v[q].y) : 0.f;
        a2 += ok ? upk(v[q].z) : 0.f;
        a3 += ok ? upk(v[q].w) : 0.f;
      }
    }
    j += batch;
  }
  const float ic = inv[node];
  uint4 o;
  o.x = pk(a0 * ic);
  o.y = pk(a1 * ic);
  o.z = pk(a2 * ic);
  o.w = pk(a3 * ic);
  *(uint4*)(apk + (size_t)node * kH + coff) = o;
}

// ---------------- MFMA GEMM: 2-barrier gload_lds, BK=64 (R14-proven) --------
// out = sum_p [ Ahi@Whi + Ahi@Wlo + Alo@Whi ](p)  (+bias) [+LN+resid]
// Tile 64 rows x 256 cols, 4 waves, 4x4 frags 16x16x32, BK=64.
// LDS = 16+32+32 = 80 KB -> 2 blocks/CU; redS/redQ alias into A tile.
struct GArgs {
  const u32* A[2];
  const ush* Wh[2];
  const ush* Wl[2];
  const float* bias;
  const float* lng;
  const float* lnb;
  const u32* rpk;
  float* outf;
  u32* opk;
  int M, npass, ostride;
};

template <bool LN>
__global__ __launch_bounds__(256, 2) void k_mg(GArgs g) {
  __shared__ u32 Apk[64 * 64];   // 16 KB (redS/redQ alias here post-loop)
  __shared__ ush Wht[256 * 64];  // 32 KB
  __shared__ ush Wlt[256 * 64];  // 32 KB

  const int tid = threadIdx.x;
  const int wv = tid >> 6;
  const int l = tid & 63;
  const int fr = l & 15, fk = l >> 4;

  int bx, by;
  if (LN) {
    bx = blockIdx.x;
    by = 0;
  } else {
    // T1 XCD-bijective swizzle: nwg = 5000 = 8 XCDs x 625. The 4 col-blocks
    // of one row-block stay consecutive ON THE SAME XCD (L2 reuse of A).
    const int w = (blockIdx.x & 7) * 625 + (blockIdx.x >> 3);
    bx = w >> 2;
    by = w & 3;
  }
  const int r0 = bx * 64;
  const int cb = by << 8;

  // fragment-read swizzled offsets per k-sub s
  int axc[2], ayc[2], wcs[2];
#pragma unroll
  for (int s = 0; s < 2; ++s) {
    axc[s] = ((s * 8 + fk * 2) ^ fr) * 4;       // u32 units
    ayc[s] = ((s * 8 + fk * 2 + 1) ^ fr) * 4;   // u32 units
    wcs[s] = ((s * 4 + fk) ^ (fr & 7)) * 8;     // ush units
  }

  // staging maps
  const int aswz = ((tid & 15) ^ (tid >> 4)) * 4;           // u32 units
  const int wswz = ((tid & 7) ^ ((tid >> 3) & 7)) * 8;      // ush units
  int arg[4];
#pragma unroll
  for (int i = 0; i < 4; ++i) {
    int r = r0 + i * 16 + (tid >> 4);
    arg[i] = (r < g.M) ? r : (g.M - 1);
  }
  const int wrow0 = tid >> 3;  // + i*32 per slot

  f32x4 acc[4][4];
#pragma unroll
  for (int m = 0; m < 4; ++m)
#pragma unroll
    for (int n = 0; n < 4; ++n) acc[m][n] = (f32x4)(0.f);

#pragma unroll 1
  for (int p = 0; p < g.npass; ++p) {
    const u32* aP = g.A[p];
    const ush* whP = g.Wh[p] + (size_t)(cb + wrow0) * kH + wswz;
    const ush* wlP = g.Wl[p] + (size_t)(cb + wrow0) * kH + wswz;
#pragma unroll 1
    for (int kc = 0; kc < kH; kc += 64) {
      __syncthreads();  // all waves done reading previous tile
#pragma unroll
      for (int i = 0; i < 4; ++i)
        gload16(aP + (size_t)arg[i] * kH + aswz + kc, Apk + (i * 256 + tid) * 4);
#pragma unroll
      for (int i = 0; i < 8; ++i) {
        gload16(whP + (size_t)i * 32 * kH + kc, Wht + (i * 256 + tid) * 8);
        gload16(wlP + (size_t)i * 32 * kH + kc, Wlt + (i * 256 + tid) * 8);
      }
      __syncthreads();  // vmcnt drained: staged data visible

#pragma unroll
      for (int s = 0; s < 2; ++s) {
        short8 ah[4], al[4], whf[4], wlf[4];
#pragma unroll
        for (int m = 0; m < 4; ++m) {
          const uint4 x = *(const uint4*)(Apk + (m * 16 + fr) * 64 + axc[s]);
          const uint4 y = *(const uint4*)(Apk + (m * 16 + fr) * 64 + ayc[s]);
          unpk8(x, y, ah[m], al[m]);
        }
#pragma unroll
        for (int n = 0; n < 4; ++n) {
          whf[n] = *(const short8*)(Wht + (wv * 64 + n * 16 + fr) * 64 + wcs[s]);
          wlf[n] = *(const short8*)(Wlt + (wv * 64 + n * 16 + fr) * 64 + wcs[s]);
        }
#pragma unroll
        for (int m = 0; m < 4; ++m)
#pragma unroll
          for (int n = 0; n < 4; ++n) {
            acc[m][n] = __builtin_amdgcn_mfma_f32_16x16x32_bf16(ah[m], whf[n],
                                                                acc[m][n], 0, 0, 0);
            acc[m][n] = __builtin_amdgcn_mfma_f32_16x16x32_bf16(ah[m], wlf[n],
                                                                acc[m][n], 0, 0, 0);
            acc[m][n] = __builtin_amdgcn_mfma_f32_16x16x32_bf16(al[m], whf[n],
                                                                acc[m][n], 0, 0, 0);
          }
      }
    }
  }

  // ---- epilogue ----
  float bn[4];
#pragma unroll
  for (int n = 0; n < 4; ++n) bn[n] = g.bias[cb + wv * 64 + n * 16 + fr];
#pragma unroll
  for (int m = 0; m < 4; ++m)
#pragma unroll
    for (int n = 0; n < 4; ++n)
#pragma unroll
      for (int j = 0; j < 4; ++j) acc[m][n][j] += bn[n];

  if (LN) {
    __syncthreads();  // other waves may still be ds_reading the final tile
    float* redS = (float*)&Apk[0];        // 256 floats
    float* redQ = ((float*)&Apk[0]) + 256;
#pragma unroll
    for (int m = 0; m < 4; ++m)
#pragma unroll
      for (int j = 0; j < 4; ++j) {
        float s = acc[m][0][j] + acc[m][1][j] + acc[m][2][j] + acc[m][3][j];
        float q = acc[m][0][j] * acc[m][0][j] + acc[m][1][j] * acc[m][1][j] +
                  acc[m][2][j] * acc[m][2][j] + acc[m][3][j] * acc[m][3][j];
#pragma unroll
        for (int d = 1; d < 16; d <<= 1) {
          s += __shfl_xor(s, d);
          q += __shfl_xor(q, d);
        }
        if (fr == 0) {
          redS[wv * 64 + m * 16 + fk * 4 + j] = s;
          redQ[wv * 64 + m * 16 + fk * 4 + j] = q;
        }
      }
    __syncthreads();
    float gg[4], eb[4];
#pragma unroll
    for (int n = 0; n < 4; ++n) {
      gg[n] = g.lng[wv * 64 + n * 16 + fr];
      eb[n] = g.lnb[wv * 64 + n * 16 + fr];
    }
#pragma unroll
    for (int m = 0; m < 4; ++m)
#pragma unroll
      for (int j = 0; j < 4; ++j) {
        const int rt = m * 16 + fk * 4 + j;
        const float S = redS[rt] + redS[64 + rt] + redS[128 + rt] + redS[192 + rt];
        const float Q = redQ[rt] + redQ[64 + rt] + redQ[128 + rt] + redQ[192 + rt];
        const float mu = S * (1.f / 256.f);
        float var = Q * (1.f / 256.f) - mu * mu;
        var = var > 0.f ? var : 0.f;
        const float rstd = rsqrtf(var + LN_EPS);
        const int ri = r0 + rt;
        if (ri < g.M) {
          const size_t base = (size_t)ri * kH + wv * 64 + fr;
#pragma unroll
          for (int n = 0; n < 4; ++n) {
            const size_t ix = base + n * 16;
            const float res = upk(g.rpk[ix]);
            const float y = (acc[m][n][j] - mu) * rstd * gg[n] + eb[n] + res;
            g.opk[ix] = pk(y);
          }
        }
      }
  } else {
#pragma unroll
    for (int m = 0; m < 4; ++m)
#pragma unroll
      for (int j = 0; j < 4; ++j) {
        const int ri = r0 + m * 16 + fk * 4 + j;
        if (ri < g.M) {
          float* op = g.outf + (size_t)ri * g.ostride + cb + wv * 64 + fr;
#pragma unroll
          for (int n = 0; n < 4; ++n) op[n * 16] = acc[m][n][j];
        }
      }
  }
}

// ---------------- weight hi/lo split (K=256 weights) ----------------
__global__ __launch_bounds__(256) void k_split(const float* __restrict__ s,
                                               ush* __restrict__ hi,
                                               ush* __restrict__ lo, int n) {
  int i = blockIdx.x * 256 + threadIdx.x;
  if (i >= n) return;
  float v = s[i];
  ush h = f2b(v);
  hi[i] = h;
  lo[i] = f2b(v - b2f(h));
}

// ---------------- host launch ----------------
extern "C" void kernel_launch(void* const* d_in, const int* in_sizes, int n_in,
                              void* d_out, int out_size, void* d_ws, size_t ws_size,
                              hipStream_t stream) {
  (void)in_sizes; (void)n_in; (void)out_size; (void)ws_size;
  const float* x_occ    = (const float*)d_in[0];
  const float* x_chord  = (const float*)d_in[1];
  const float* x_sec    = (const float*)d_in[2];
  const float* x_note   = (const float*)d_in[3];
  const float* x_sd     = (const float*)d_in[4];
  const int* ei[10];
  for (int i = 0; i < 10; ++i) ei[i] = (const int*)d_in[5 + i];
  const float* W_occ    = (const float*)d_in[15];
  const float* b_occ    = (const float*)d_in[16];
  const float* W_chord  = (const float*)d_in[17];
  const float* b_chord  = (const float*)d_in[18];
  const float* W_sec    = (const float*)d_in[19];
  const float* b_sec    = (const float*)d_in[20];
  const float* W_note   = (const float*)d_in[21];
  const float* b_note   = (const float*)d_in[22];
  const float* W_sd     = (const float*)d_in[23];
  const float* b_sd     = (const float*)d_in[24];
  const float* type_emb = (const float*)d_in[25];
  const float* Wl       = (const float*)d_in[26];
  const float* bl       = (const float*)d_in[27];
  const float* Wr       = (const float*)d_in[28];
  const float* ln_g     = (const float*)d_in[29];
  const float* ln_b     = (const float*)d_in[30];
  const float* Wc       = (const float*)d_in[31];
  const float* bc       = (const float*)d_in[32];

  char* base = (char*)d_ws;
  u32* h_pk   = (u32*)(base);                  // 108,083,200 B
  char* R = base + 108083200u;                 // agg_pk region (108 MB)
  u32* agg_pk = (u32*)R;
  char* wb = base + 216166400u;
  ush* Wl_hi = (ush*)(wb);
  ush* Wl_lo = (ush*)(wb + 393216u);
  ush* Wr_hi = (ush*)(wb + 786432u);
  ush* Wr_lo = (ush*)(wb + 1179648u);
  ush* Wc_hi = (ush*)(wb + 1572864u);
  ush* Wc_lo = (ush*)(wb + 2097152u);
  // padded proj weights [256][Kp] hi/lo
  ush* Wo_hi = (ush*)(wb + 2621440u);          // Kp=96: 49,152 B
  ush* Wo_lo = (ush*)(wb + 2670592u);
  ush* Wch_hi = (ush*)(wb + 2719744u);         // Kp=32: 16,384 B
  ush* Wch_lo = (ush*)(wb + 2736128u);
  ush* Wse_hi = (ush*)(wb + 2752512u);
  ush* Wse_lo = (ush*)(wb + 2768896u);
  ush* Wnt_hi = (ush*)(wb + 2785280u);
  ush* Wnt_lo = (ush*)(wb + 2801664u);
  ush* Wsd_hi = (ush*)(wb + 2818048u);
  ush* Wsd_lo = (ush*)(wb + 2834432u);
  int* ip = (int*)(wb + 2850816u);
  int* csr_src = ip;
  int* cnt     = ip + 605000;
  int* rowptr  = ip + 710550;
  int* cursor  = ip + 816101;
  float* inv   = (float*)(ip + 921651);
  int* bsum    = ip + 1027201;
  int* bscan   = ip + 1027614;
  // transient aliases inside agg_pk region (dead before first k_agg):
  float* cpo  = (float*)(R);                   // 10,240,000 B
  int* winner = (int*)(R + 10240000u);         // 320,000 B
  int* src_g  = (int*)(R + 10560000u);         // 2,420,000 B
  int* dst_g  = (int*)(R + 12980000u);         // 2,420,000 B
  u32* Xp_occ = (u32*)(R + 16000000u);         // 30,720,000 B
  u32* Xp_ch  = (u32*)(R + 46720000u);         // 2,560,000 B
  u32* Xp_se  = (u32*)(R + 49280000u);         // 640,000 B
  u32* Xp_nt  = (u32*)(R + 49920000u);         // 64,000 B
  u32* Xp_sd  = (u32*)(R + 49984000u);         // 6,400 B

  hipMemsetAsync(winner, 0xFF, kNo * 4, stream);
  hipMemsetAsync(cpo, 0, (size_t)kNo * 32 * 4, stream);
  hipMemsetAsync(cnt, 0, kN * 4, stream);

  // layer + classifier weight splits
  k_split<<<768, 256, 0, stream>>>(Wl, Wl_hi, Wl_lo, 3 * kH * kH);
  k_split<<<768, 256, 0, stream>>>(Wr, Wr_hi, Wr_lo, 3 * kH * kH);
  k_split<<<1024, 256, 0, stream>>>(Wc, Wc_hi, Wc_lo, kC * kH);

  // proj weight split + pad
  k_wsplit<<<(256 * 96 + 255) / 256, 256, 0, stream>>>(W_occ, 96, 96, Wo_hi, Wo_lo);
  k_wsplit<<<32, 256, 0, stream>>>(W_chord, 32, 32, Wch_hi, Wch_lo);
  k_wsplit<<<32, 256, 0, stream>>>(W_sec, 16, 32, Wse_hi, Wse_lo);
  k_wsplit<<<32, 256, 0, stream>>>(W_note, 16, 32, Wnt_hi, Wnt_lo);
  k_wsplit<<<32, 256, 0, stream>>>(W_sd, 8, 32, Wsd_hi, Wsd_lo);

  // chord -> occ feature scatter (numpy last-writer-wins)
  k_winner<<<(kNo + 255) / 256, 256, 0, stream>>>(ei[2], winner);
  k_scat<<<(kNo * 8) / 256, 256, 0, stream>>>(ei[2], winner, x_chord, cpo);

  // pack inputs (occ after cpo ready)
  k_pack2<<<(kNo * 96 + 255) / 256, 256, 0, stream>>>(x_occ, 64, cpo, 32, 96, Xp_occ, kNo);
  k_pack2<<<(kNc * 32 + 255) / 256, 256, 0, stream>>>(x_chord, 32, nullptr, 0, 32, Xp_ch, kNc);
  k_pack2<<<(kNs * 32 + 255) / 256, 256, 0, stream>>>(x_sec, 16, nullptr, 0, 32, Xp_se, kNs);
  k_pack2<<<(kNn * 32 + 255) / 256, 256, 0, stream>>>(x_note, 16, nullptr, 0, 32, Xp_nt, kNn);
  k_pack2<<<(kNd * 32 + 255) / 256, 256, 0, stream>>>(x_sd, 8, nullptr, 0, 32, Xp_sd, kNd);

  // MFMA projections -> h_pk
  {
    PArgs p{};
    p.Xp = Xp_occ; p.Wh = Wo_hi; p.Wlo = Wo_lo; p.bias = b_occ;
    p.emb = type_emb + 0 * kH; p.out = h_pk; p.M = kNo; p.Kp = 96;
    k_pmg<<<(kNo + 63) / 64, 256, 0, stream>>>(p);
    p.Xp = Xp_ch; p.Wh = Wch_hi; p.Wlo = Wch_lo; p.bias = b_chord;
    p.emb = type_emb + 1 * kH; p.out = h_pk + (size_t)kNo * kH; p.M = kNc; p.Kp = 32;
    k_pmg<<<(kNc + 63) / 64, 256, 0, stream>>>(p);
    p.Xp = Xp_se; p.Wh = Wse_hi; p.Wlo = Wse_lo; p.bias = b_sec;
    p.emb = type_emb + 2 * kH; p.out = h_pk + (size_t)100000 * kH; p.M = kNs; p.Kp = 32;
    k_pmg<<<(kNs + 63) / 64, 256, 0, stream>>>(p);
    p.Xp = Xp_nt; p.Wh = Wnt_hi; p.Wlo = Wnt_lo; p.bias = b_note;
    p.emb = type_emb + 3 * kH; p.out = h_pk + (size_t)105000 * kH; p.M = kNn; p.Kp = 32;
    k_pmg<<<(kNn + 63) / 64, 256, 0, stream>>>(p);
    p.Xp = Xp_sd; p.Wh = Wsd_hi; p.Wlo = Wsd_lo; p.bias = b_sd;
    p.emb = type_emb + 4 * kH; p.out = h_pk + (size_t)105500 * kH; p.M = kNd; p.Kp = 32;
    k_pmg<<<(kNd + 63) / 64, 256, 0, stream>>>(p);
  }

  // homogeneous edge list + CSR
  EdgeTab tab;
  const int ns_[10]  = {80000, 80000, 80000, 80000, 80000, 5000, 80000, 80000, 20000, 20000};
  const int sos_[10] = {0, 0, 80000, 0, 100000, 100000, 80000, 105000, 80000, 105500};
  const int dos_[10] = {0, 80000, 0, 100000, 0, 100000, 105000, 80000, 105500, 80000};
  int cum = 0;
  for (int i = 0; i < 10; ++i) {
    tab.p[i] = ei[i]; tab.n[i] = ns_[i]; tab.so[i] = sos_[i]; tab.dofs[i] = dos_[i];
    tab.cum[i] = cum; cum += ns_[i];
  }
  tab.cum[10] = cum;

  k_edges<<<(kE + 255) / 256, 256, 0, stream>>>(tab, src_g, dst_g, cnt);
  k_scan1<<<NBLK, 256, 0, stream>>>(cnt, bsum);
  k_scan2<<<1, 512, 0, stream>>>(bsum, bscan);
  k_scan3<<<NBLK, 256, 0, stream>>>(cnt, bscan, rowptr, cursor, inv);
  k_fill<<<(kE + 255) / 256, 256, 0, stream>>>(src_g, dst_g, cursor, csr_src);

  // 3 SAGE layers
  for (int l = 0; l < 3; ++l) {
    k_agg<<<(kN + 15) / 16, 1024, 0, stream>>>(h_pk, rowptr, csr_src, inv, agg_pk);
    GArgs a{};
    const size_t off = (size_t)l * kH * kH;
    a.A[0] = agg_pk;      a.A[1] = h_pk;
    a.Wh[0] = Wl_hi + off; a.Wh[1] = Wr_hi + off;
    a.Wl[0] = Wl_lo + off; a.Wl[1] = Wr_lo + off;
    a.bias = bl + l * kH;
    a.lng = ln_g + l * kH;
    a.lnb = ln_b + l * kH;
    a.rpk = h_pk;
    a.outf = nullptr;
    a.opk = h_pk;
    a.M = kN; a.npass = 2; a.ostride = kH;
    k_mg<true><<<dim3((kN + 63) / 64, 1), 256, 0, stream>>>(a);
  }

  // classifier head over occ nodes (1-D grid, XCD-bijective + col-inner)
  GArgs c{};
  c.A[0] = h_pk;
  c.Wh[0] = Wc_hi;
  c.Wl[0] = Wc_lo;
  c.bias = bc;
  c.rpk = nullptr;
  c.outf = (float*)d_out;
  c.opk = nullptr;
  c.M = kNo; c.npass = 1; c.ostride = kC;
  k_mg<false><<<(kNo / 64) * 4, 256, 0, stream>>>(c);
}

// Round 16
// 1147.956 us; speedup vs baseline: 1.0698x; 1.0698x over previous
//
#include <hip/hip_runtime.h>

// HomoMusicGNN: 3-layer mean-SAGE GNN + LN + residual + 1024-way head.
// Round 16: exact revert to R14 (session best, 1154 us). k_agg back to 256
// threads (4 nodes/block, 1 node/wave) -- R15's 1024-thread block regressed
// via block-retirement imbalance (heavy-tail nodes grouped into few blocks).
// k_mg = BK=64 2-barrier gload_lds; classifier XCD-bijective grid.

#define kNo 80000
#define kNc 20000
#define kNs 5000
#define kNn 500
#define kNd 50
#define kN  105550
#define kH  256
#define kC  1024
#define kE  605000
#define LN_EPS 1e-5f
#define NBLK 413  // ceil(kN/256)

typedef unsigned int u32;
typedef unsigned short ush;
typedef __attribute__((ext_vector_type(8))) short short8;
typedef __attribute__((ext_vector_type(4))) float f32x4;

__device__ __forceinline__ float b2f(ush b) {
  u32 u = ((u32)b) << 16;
  float f;
  __builtin_memcpy(&f, &u, 4);
  return f;
}
__device__ __forceinline__ ush f2b(float x) {
  u32 u;
  __builtin_memcpy(&u, &x, 4);
  u32 r = (u + 0x7fffu + ((u >> 16) & 1u)) >> 16;
  return (ush)r;
}
__device__ __forceinline__ float up_hi(u32 u) {
  u32 v = u & 0xffff0000u;
  float f;
  __builtin_memcpy(&f, &v, 4);
  return f;
}
__device__ __forceinline__ float up_lo(u32 u) {
  u32 v = u << 16;
  float f;
  __builtin_memcpy(&f, &v, 4);
  return f;
}
__device__ __forceinline__ float upk(u32 u) { return up_hi(u) + up_lo(u); }
__device__ __forceinline__ u32 pk(float x) {
  ush hi = f2b(x);
  ush lo = f2b(x - b2f(hi));
  return (((u32)hi) << 16) | (u32)lo;
}

union S8u {
  u32 w[4];
  short8 s;
};
// 8 packed cols (a=cols k0..k3, b=k4..k7) -> hi short8 + lo short8
__device__ __forceinline__ void unpk8(uint4 a, uint4 b, short8& hi, short8& lo) {
  S8u h, l;
  h.w[0] = (a.x >> 16) | (a.y & 0xffff0000u);
  h.w[1] = (a.z >> 16) | (a.w & 0xffff0000u);
  h.w[2] = (b.x >> 16) | (b.y & 0xffff0000u);
  h.w[3] = (b.z >> 16) | (b.w & 0xffff0000u);
  l.w[0] = (a.x & 0xffffu) | (a.y << 16);
  l.w[1] = (a.z & 0xffffu) | (a.w << 16);
  l.w[2] = (b.x & 0xffffu) | (b.y << 16);
  l.w[3] = (b.z & 0xffffu) | (b.w << 16);
  hi = h.s;
  lo = l.s;
}

__device__ __forceinline__ void gload16(const void* g, void* l) {
  __builtin_amdgcn_global_load_lds((const __attribute__((address_space(1))) u32*)g,
                                   (__attribute__((address_space(3))) u32*)l, 16, 0, 0);
}

struct EdgeTab {
  const int* p[10];
  int n[10], so[10], dofs[10], cum[11];
};

// ---------------- edge flatten + in-degree count ----------------
__global__ __launch_bounds__(256) void k_edges(EdgeTab t, int* __restrict__ src_g,
                                               int* __restrict__ dst_g,
                                               int* __restrict__ cnt) {
  int e = blockIdx.x * 256 + threadIdx.x;
  if (e >= kE) return;
  int s = 0;
#pragma unroll
  for (int i = 1; i < 10; ++i) s += (e >= t.cum[i]) ? 1 : 0;
  int j = e - t.cum[s];
  const int* p = t.p[s];
  int src = p[j] + t.so[s];
  int dst = p[t.n[s] + j] + t.dofs[s];
  src_g[e] = src;
  dst_g[e] = dst;
  atomicAdd(&cnt[dst], 1);
}

// ---------------- last-writer-wins scatter-set (chord feats -> occ) ----------
__global__ __launch_bounds__(256) void k_winner(const int* __restrict__ ei,
                                                int* __restrict__ winner) {
  int e = blockIdx.x * 256 + threadIdx.x;
  if (e >= kNo) return;
  atomicMax(&winner[ei[kNo + e]], e);
}

__global__ __launch_bounds__(256) void k_scat(const int* __restrict__ ei,
                                              const int* __restrict__ winner,
                                              const float* __restrict__ xch,
                                              float* __restrict__ cpo) {
  int tid = blockIdx.x * 256 + threadIdx.x;
  if (tid >= kNo * 8) return;
  int e = tid >> 3, q = tid & 7;
  int d = ei[kNo + e];
  if (winner[d] == e) {
    int s = ei[e];
    ((float4*)cpo)[d * 8 + q] = ((const float4*)xch)[s * 8 + q];
  }
}

// ---------------- input pack: [M][Kp] u32 (hi<<16|lo), zero-padded ----------
__global__ __launch_bounds__(256) void k_pack2(const float* __restrict__ A1, int K1,
                                               const float* __restrict__ A2, int K2,
                                               int Kp, u32* __restrict__ Xp, int M) {
  int tid = blockIdx.x * 256 + threadIdx.x;
  if (tid >= M * Kp) return;
  int r = tid / Kp, c = tid - r * Kp;
  float v = 0.f;
  if (c < K1) v = A1[(size_t)r * K1 + c];
  else if (c < K1 + K2) v = A2[(size_t)r * K2 + (c - K1)];
  Xp[tid] = pk(v);
}

// ---------------- weight split + pad: [256][Kp] hi/lo bf16 ----------------
__global__ __launch_bounds__(256) void k_wsplit(const float* __restrict__ W, int K,
                                                int Kp, ush* __restrict__ hi,
                                                ush* __restrict__ lo) {
  int tid = blockIdx.x * 256 + threadIdx.x;
  if (tid >= 256 * Kp) return;
  int r = tid / Kp, c = tid - r * Kp;
  float v = (c < K) ? W[(size_t)r * K + c] : 0.f;
  ush h = f2b(v);
  hi[tid] = h;
  lo[tid] = f2b(v - b2f(h));
}

// ---------------- MFMA projection: Xp(packed) @ W^T + bias + emb -> h_pk ----
struct PArgs {
  const u32* Xp;     // [M][Kp] packed
  const ush* Wh;     // [256][Kp]
  const ush* Wlo;    // [256][Kp]
  const float* bias; // [256]
  const float* emb;  // [256]
  u32* out;          // h_pk + rowbase*kH
  int M, Kp;
};

__global__ __launch_bounds__(256) void k_pmg(PArgs g) {
  __shared__ u32 Apk[64 * 32];   // 8 KB
  __shared__ ush Wht[256 * 32];  // 16 KB
  __shared__ ush Wlt[256 * 32];  // 16 KB

  const int tid = threadIdx.x;
  const int wv = tid >> 6;
  const int l = tid & 63;
  const int fr = l & 15, fk = l >> 4;
  const int r0 = blockIdx.x * 64;

  const int ac0 = (((fk * 2) ^ (fr & 7)) * 4);
  const int ac1 = (((fk * 2 + 1) ^ (fr & 7)) * 4);
  const int wc8 = ((fk ^ (fr & 3)) * 8);

  const int arow = tid >> 3, ach = tid & 7;
  const int wrow = tid >> 2, wch = tid & 3;
  const int ar0g = (r0 + arow < g.M) ? (r0 + arow) : (g.M - 1);
  const int ar1g = (r0 + arow + 32 < g.M) ? (r0 + arow + 32) : (g.M - 1);
  const int aswz = (ach ^ (arow & 7)) * 4;
  const int wswz = (wch ^ (wrow & 3)) * 8;

  f32x4 acc[4][4];
#pragma unroll
  for (int m = 0; m < 4; ++m)
#pragma unroll
    for (int n = 0; n < 4; ++n) acc[m][n] = (f32x4)(0.f);

  const u32* a0 = g.Xp + (size_t)ar0g * g.Kp + aswz;
  const u32* a1 = g.Xp + (size_t)ar1g * g.Kp + aswz;
  const ush* wh = g.Wh + (size_t)wrow * g.Kp + wswz;
  const ush* wl = g.Wlo + (size_t)wrow * g.Kp + wswz;

#pragma unroll 1
  for (int kc = 0; kc < g.Kp; kc += 32) {
    __syncthreads();
    gload16(a0 + kc, Apk + tid * 4);
    gload16(a1 + kc, Apk + (tid + 256) * 4);
#pragma unroll
    for (int i = 0; i < 4; ++i) {
      gload16(wh + (size_t)i * 64 * g.Kp + kc, Wht + (tid + i * 256) * 8);
      gload16(wl + (size_t)i * 64 * g.Kp + kc, Wlt + (tid + i * 256) * 8);
    }
    __syncthreads();

    short8 ah[4], al[4], whf[4], wlf[4];
#pragma unroll
    for (int m = 0; m < 4; ++m) {
      const uint4 x = *(const uint4*)(Apk + (m * 16 + fr) * 32 + ac0);
      const uint4 y = *(const uint4*)(Apk + (m * 16 + fr) * 32 + ac1);
      unpk8(x, y, ah[m], al[m]);
    }
#pragma unroll
    for (int n = 0; n < 4; ++n) {
      whf[n] = *(const short8*)(Wht + (wv * 64 + n * 16 + fr) * 32 + wc8);
      wlf[n] = *(const short8*)(Wlt + (wv * 64 + n * 16 + fr) * 32 + wc8);
    }
#pragma unroll
    for (int m = 0; m < 4; ++m)
#pragma unroll
      for (int n = 0; n < 4; ++n) {
        acc[m][n] = __builtin_amdgcn_mfma_f32_16x16x32_bf16(ah[m], whf[n],
                                                            acc[m][n], 0, 0, 0);
        acc[m][n] = __builtin_amdgcn_mfma_f32_16x16x32_bf16(ah[m], wlf[n],
                                                            acc[m][n], 0, 0, 0);
        acc[m][n] = __builtin_amdgcn_mfma_f32_16x16x32_bf16(al[m], whf[n],
                                                            acc[m][n], 0, 0, 0);
      }
  }

  float bn[4];
#pragma unroll
  for (int n = 0; n < 4; ++n) {
    const int col = wv * 64 + n * 16 + fr;
    bn[n] = g.bias[col] + g.emb[col];
  }
#pragma unroll
  for (int m = 0; m < 4; ++m)
#pragma unroll
    for (int j = 0; j < 4; ++j) {
      const int ri = r0 + m * 16 + fk * 4 + j;
      if (ri < g.M) {
        u32* op = g.out + (size_t)ri * kH + wv * 64 + fr;
#pragma unroll
        for (int n = 0; n < 4; ++n) op[n * 16] = pk(acc[m][n][j] + bn[n]);
      }
    }
}

// ---------------- CSR build ----------------
__global__ __launch_bounds__(256) void k_scan1(const int* __restrict__ cnt,
                                               int* __restrict__ bsum) {
  __shared__ int s[256];
  int b = blockIdx.x, t = threadIdx.x;
  int i = b * 256 + t;
  s[t] = (i < kN) ? cnt[i] : 0;
  __syncthreads();
  for (int off = 128; off; off >>= 1) {
    if (t < off) s[t] += s[t + off];
    __syncthreads();
  }
  if (t == 0) bsum[b] = s[0];
}

__global__ __launch_bounds__(512) void k_scan2(const int* __restrict__ bsum,
                                               int* __restrict__ bscan) {
  __shared__ int s[512];
  int t = threadIdx.x;
  s[t] = (t < NBLK) ? bsum[t] : 0;
  __syncthreads();
  for (int off = 1; off < 512; off <<= 1) {
    int v = (t >= off) ? s[t - off] : 0;
    __syncthreads();
    s[t] += v;
    __syncthreads();
  }
  if (t < NBLK) bscan[t] = s[t];
}

__global__ __launch_bounds__(256) void k_scan3(const int* __restrict__ cnt,
                                               const int* __restrict__ bscan,
                                               int* __restrict__ rowptr,
                                               int* __restrict__ cursor,
                                               float* __restrict__ inv) {
  __shared__ int s[256];
  int b = blockIdx.x, t = threadIdx.x;
  int i = b * 256 + t;
  int v = (i < kN) ? cnt[i] : 0;
  s[t] = v;
  __syncthreads();
  for (int off = 1; off < 256; off <<= 1) {
    int u = (t >= off) ? s[t - off] : 0;
    __syncthreads();
    s[t] += u;
    __syncthreads();
  }
  int incl = s[t];
  int base = (b > 0) ? bscan[b - 1] : 0;
  int excl = base + incl - v;
  if (i < kN) {
    rowptr[i] = excl;
    cursor[i] = excl;
    inv[i] = 1.f / (float)(v > 1 ? v : 1);
    if (i == kN - 1) rowptr[kN] = excl + v;
  }
}

__global__ __launch_bounds__(256) void k_fill(const int* __restrict__ src_g,
                                              const int* __restrict__ dst_g,
                                              int* __restrict__ cursor,
                                              int* __restrict__ csr_src) {
  int e = blockIdx.x * 256 + threadIdx.x;
  if (e >= kE) return;
  int d = dst_g[e];
  int slot = atomicAdd(&cursor[d], 1);
  csr_src[slot] = src_g[e];
}

// ------- pull-mode mean aggregation: 1 node/wave, branch-free batch-of-8 ----
__global__ __launch_bounds__(256) void k_agg(const u32* __restrict__ hpk,
                                             const int* __restrict__ rowptr,
                                             const int* __restrict__ csr_src,
                                             const float* __restrict__ inv,
                                             u32* __restrict__ apk) {
  const int wave = threadIdx.x >> 6, lane = threadIdx.x & 63;
  const int node = kN - 1 - (blockIdx.x * 4 + wave);
  if (node < 0) return;
  const int jb = rowptr[node], je = rowptr[node + 1];
  float a0 = 0.f, a1 = 0.f, a2 = 0.f, a3 = 0.f;
  const int coff = lane * 4;  // u32 col offset (16B/lane)

  int j = jb;
  while (j < je) {
    const int batch = min(je - j, 64);
    const int myi = csr_src[j + ((lane < batch) ? lane : (batch - 1))];
#pragma unroll 1
    for (int t0 = 0; t0 < batch; t0 += 8) {
      int s[8];
#pragma unroll
      for (int q = 0; q < 8; ++q) {
        const int tt = t0 + q;
        s[q] = __shfl(myi, (tt < batch) ? tt : 0);
      }
      uint4 v[8];
#pragma unroll
      for (int q = 0; q < 8; ++q)
        v[q] = *(const uint4*)(hpk + (size_t)s[q] * kH + coff);
#pragma unroll
      for (int q = 0; q < 8; ++q) {
        const bool ok = (t0 + q) < batch;  // wave-uniform, branch-free select
        a0 += ok ? upk(v[q].x) : 0.f;
        a1 += ok ? upk(v[q].y) : 0.f;
        a2 += ok ? upk(v[q].z) : 0.f;
        a3 += ok ? upk(v[q].w) : 0.f;
      }
    }
    j += batch;
  }
  const float ic = inv[node];
  uint4 o;
  o.x = pk(a0 * ic);
  o.y = pk(a1 * ic);
  o.z = pk(a2 * ic);
  o.w = pk(a3 * ic);
  *(uint4*)(apk + (size_t)node * kH + coff) = o;
}

// ---------------- MFMA GEMM: 2-barrier gload_lds, BK=64 ----------------
// out = sum_p [ Ahi@Whi + Ahi@Wlo + Alo@Whi ](p)  (+bias) [+LN+resid]
// Tile 64 rows x 256 cols, 4 waves, 4x4 frags 16x16x32, BK=64.
// LDS = 16+32+32 = 80 KB -> 2 blocks/CU; redS/redQ alias into A tile.
struct GArgs {
  const u32* A[2];
  const ush* Wh[2];
  const ush* Wl[2];
  const float* bias;
  const float* lng;
  const float* lnb;
  const u32* rpk;
  float* outf;
  u32* opk;
  int M, npass, ostride;
};

template <bool LN>
__global__ __launch_bounds__(256, 2) void k_mg(GArgs g) {
  __shared__ u32 Apk[64 * 64];   // 16 KB (redS/redQ alias here post-loop)
  __shared__ ush Wht[256 * 64];  // 32 KB
  __shared__ ush Wlt[256 * 64];  // 32 KB

  const int tid = threadIdx.x;
  const int wv = tid >> 6;
  const int l = tid & 63;
  const int fr = l & 15, fk = l >> 4;

  int bx, by;
  if (LN) {
    bx = blockIdx.x;
    by = 0;
  } else {
    // T1 XCD-bijective swizzle: nwg = 5000 = 8 XCDs x 625. The 4 col-blocks
    // of one row-block stay consecutive ON THE SAME XCD (L2 reuse of A).
    const int w = (blockIdx.x & 7) * 625 + (blockIdx.x >> 3);
    bx = w >> 2;
    by = w & 3;
  }
  const int r0 = bx * 64;
  const int cb = by << 8;

  // fragment-read swizzled offsets per k-sub s
  int axc[2], ayc[2], wcs[2];
#pragma unroll
  for (int s = 0; s < 2; ++s) {
    axc[s] = ((s * 8 + fk * 2) ^ fr) * 4;       // u32 units
    ayc[s] = ((s * 8 + fk * 2 + 1) ^ fr) * 4;   // u32 units
    wcs[s] = ((s * 4 + fk) ^ (fr & 7)) * 8;     // ush units
  }

  // staging maps
  const int aswz = ((tid & 15) ^ (tid >> 4)) * 4;           // u32 units
  const int wswz = ((tid & 7) ^ ((tid >> 3) & 7)) * 8;      // ush units
  int arg[4];
#pragma unroll
  for (int i = 0; i < 4; ++i) {
    int r = r0 + i * 16 + (tid >> 4);
    arg[i] = (r < g.M) ? r : (g.M - 1);
  }
  const int wrow0 = tid >> 3;  // + i*32 per slot

  f32x4 acc[4][4];
#pragma unroll
  for (int m = 0; m < 4; ++m)
#pragma unroll
    for (int n = 0; n < 4; ++n) acc[m][n] = (f32x4)(0.f);

#pragma unroll 1
  for (int p = 0; p < g.npass; ++p) {
    const u32* aP = g.A[p];
    const ush* whP = g.Wh[p] + (size_t)(cb + wrow0) * kH + wswz;
    const ush* wlP = g.Wl[p] + (size_t)(cb + wrow0) * kH + wswz;
#pragma unroll 1
    for (int kc = 0; kc < kH; kc += 64) {
      __syncthreads();  // all waves done reading previous tile
#pragma unroll
      for (int i = 0; i < 4; ++i)
        gload16(aP + (size_t)arg[i] * kH + aswz + kc, Apk + (i * 256 + tid) * 4);
#pragma unroll
      for (int i = 0; i < 8; ++i) {
        gload16(whP + (size_t)i * 32 * kH + kc, Wht + (i * 256 + tid) * 8);
        gload16(wlP + (size_t)i * 32 * kH + kc, Wlt + (i * 256 + tid) * 8);
      }
      __syncthreads();  // vmcnt drained: staged data visible

#pragma unroll
      for (int s = 0; s < 2; ++s) {
        short8 ah[4], al[4], whf[4], wlf[4];
#pragma unroll
        for (int m = 0; m < 4; ++m) {
          const uint4 x = *(const uint4*)(Apk + (m * 16 + fr) * 64 + axc[s]);
          const uint4 y = *(const uint4*)(Apk + (m * 16 + fr) * 64 + ayc[s]);
          unpk8(x, y, ah[m], al[m]);
        }
#pragma unroll
        for (int n = 0; n < 4; ++n) {
          whf[n] = *(const short8*)(Wht + (wv * 64 + n * 16 + fr) * 64 + wcs[s]);
          wlf[n] = *(const short8*)(Wlt + (wv * 64 + n * 16 + fr) * 64 + wcs[s]);
        }
#pragma unroll
        for (int m = 0; m < 4; ++m)
#pragma unroll
          for (int n = 0; n < 4; ++n) {
            acc[m][n] = __builtin_amdgcn_mfma_f32_16x16x32_bf16(ah[m], whf[n],
                                                                acc[m][n], 0, 0, 0);
            acc[m][n] = __builtin_amdgcn_mfma_f32_16x16x32_bf16(ah[m], wlf[n],
                                                                acc[m][n], 0, 0, 0);
            acc[m][n] = __builtin_amdgcn_mfma_f32_16x16x32_bf16(al[m], whf[n],
                                                                acc[m][n], 0, 0, 0);
          }
      }
    }
  }

  // ---- epilogue ----
  float bn[4];
#pragma unroll
  for (int n = 0; n < 4; ++n) bn[n] = g.bias[cb + wv * 64 + n * 16 + fr];
#pragma unroll
  for (int m = 0; m < 4; ++m)
#pragma unroll
    for (int n = 0; n < 4; ++n)
#pragma unroll
      for (int j = 0; j < 4; ++j) acc[m][n][j] += bn[n];

  if (LN) {
    __syncthreads();  // other waves may still be ds_reading the final tile
    float* redS = (float*)&Apk[0];        // 256 floats
    float* redQ = ((float*)&Apk[0]) + 256;
#pragma unroll
    for (int m = 0; m < 4; ++m)
#pragma unroll
      for (int j = 0; j < 4; ++j) {
        float s = acc[m][0][j] + acc[m][1][j] + acc[m][2][j] + acc[m][3][j];
        float q = acc[m][0][j] * acc[m][0][j] + acc[m][1][j] * acc[m][1][j] +
                  acc[m][2][j] * acc[m][2][j] + acc[m][3][j] * acc[m][3][j];
#pragma unroll
        for (int d = 1; d < 16; d <<= 1) {
          s += __shfl_xor(s, d);
          q += __shfl_xor(q, d);
        }
        if (fr == 0) {
          redS[wv * 64 + m * 16 + fk * 4 + j] = s;
          redQ[wv * 64 + m * 16 + fk * 4 + j] = q;
        }
      }
    __syncthreads();
    float gg[4], eb[4];
#pragma unroll
    for (int n = 0; n < 4; ++n) {
      gg[n] = g.lng[wv * 64 + n * 16 + fr];
      eb[n] = g.lnb[wv * 64 + n * 16 + fr];
    }
#pragma unroll
    for (int m = 0; m < 4; ++m)
#pragma unroll
      for (int j = 0; j < 4; ++j) {
        const int rt = m * 16 + fk * 4 + j;
        const float S = redS[rt] + redS[64 + rt] + redS[128 + rt] + redS[192 + rt];
        const float Q = redQ[rt] + redQ[64 + rt] + redQ[128 + rt] + redQ[192 + rt];
        const float mu = S * (1.f / 256.f);
        float var = Q * (1.f / 256.f) - mu * mu;
        var = var > 0.f ? var : 0.f;
        const float rstd = rsqrtf(var + LN_EPS);
        const int ri = r0 + rt;
        if (ri < g.M) {
          const size_t base = (size_t)ri * kH + wv * 64 + fr;
#pragma unroll
          for (int n = 0; n < 4; ++n) {
            const size_t ix = base + n * 16;
            const float res = upk(g.rpk[ix]);
            const float y = (acc[m][n][j] - mu) * rstd * gg[n] + eb[n] + res;
            g.opk[ix] = pk(y);
          }
        }
      }
  } else {
#pragma unroll
    for (int m = 0; m < 4; ++m)
#pragma unroll
      for (int j = 0; j < 4; ++j) {
        const int ri = r0 + m * 16 + fk * 4 + j;
        if (ri < g.M) {
          float* op = g.outf + (size_t)ri * g.ostride + cb + wv * 64 + fr;
#pragma unroll
          for (int n = 0; n < 4; ++n) op[n * 16] = acc[m][n][j];
        }
      }
  }
}

// ---------------- weight hi/lo split (K=256 weights) ----------------
__global__ __launch_bounds__(256) void k_split(const float* __restrict__ s,
                                               ush* __restrict__ hi,
                                               ush* __restrict__ lo, int n) {
  int i = blockIdx.x * 256 + threadIdx.x;
  if (i >= n) return;
  float v = s[i];
  ush h = f2b(v);
  hi[i] = h;
  lo[i] = f2b(v - b2f(h));
}

// ---------------- host launch ----------------
extern "C" void kernel_launch(void* const* d_in, const int* in_sizes, int n_in,
                              void* d_out, int out_size, void* d_ws, size_t ws_size,
                              hipStream_t stream) {
  (void)in_sizes; (void)n_in; (void)out_size; (void)ws_size;
  const float* x_occ    = (const float*)d_in[0];
  const float* x_chord  = (const float*)d_in[1];
  const float* x_sec    = (const float*)d_in[2];
  const float* x_note   = (const float*)d_in[3];
  const float* x_sd     = (const float*)d_in[4];
  const int* ei[10];
  for (int i = 0; i < 10; ++i) ei[i] = (const int*)d_in[5 + i];
  const float* W_occ    = (const float*)d_in[15];
  const float* b_occ    = (const float*)d_in[16];
  const float* W_chord  = (const float*)d_in[17];
  const float* b_chord  = (const float*)d_in[18];
  const float* W_sec    = (const float*)d_in[19];
  const float* b_sec    = (const float*)d_in[20];
  const float* W_note   = (const float*)d_in[21];
  const float* b_note   = (const float*)d_in[22];
  const float* W_sd     = (const float*)d_in[23];
  const float* b_sd     = (const float*)d_in[24];
  const float* type_emb = (const float*)d_in[25];
  const float* Wl       = (const float*)d_in[26];
  const float* bl       = (const float*)d_in[27];
  const float* Wr       = (const float*)d_in[28];
  const float* ln_g     = (const float*)d_in[29];
  const float* ln_b     = (const float*)d_in[30];
  const float* Wc       = (const float*)d_in[31];
  const float* bc       = (const float*)d_in[32];

  char* base = (char*)d_ws;
  u32* h_pk   = (u32*)(base);                  // 108,083,200 B
  char* R = base + 108083200u;                 // agg_pk region (108 MB)
  u32* agg_pk = (u32*)R;
  char* wb = base + 216166400u;
  ush* Wl_hi = (ush*)(wb);
  ush* Wl_lo = (ush*)(wb + 393216u);
  ush* Wr_hi = (ush*)(wb + 786432u);
  ush* Wr_lo = (ush*)(wb + 1179648u);
  ush* Wc_hi = (ush*)(wb + 1572864u);
  ush* Wc_lo = (ush*)(wb + 2097152u);
  // padded proj weights [256][Kp] hi/lo
  ush* Wo_hi = (ush*)(wb + 2621440u);          // Kp=96: 49,152 B
  ush* Wo_lo = (ush*)(wb + 2670592u);
  ush* Wch_hi = (ush*)(wb + 2719744u);         // Kp=32: 16,384 B
  ush* Wch_lo = (ush*)(wb + 2736128u);
  ush* Wse_hi = (ush*)(wb + 2752512u);
  ush* Wse_lo = (ush*)(wb + 2768896u);
  ush* Wnt_hi = (ush*)(wb + 2785280u);
  ush* Wnt_lo = (ush*)(wb + 2801664u);
  ush* Wsd_hi = (ush*)(wb + 2818048u);
  ush* Wsd_lo = (ush*)(wb + 2834432u);
  int* ip = (int*)(wb + 2850816u);
  int* csr_src = ip;
  int* cnt     = ip + 605000;
  int* rowptr  = ip + 710550;
  int* cursor  = ip + 816101;
  float* inv   = (float*)(ip + 921651);
  int* bsum    = ip + 1027201;
  int* bscan   = ip + 1027614;
  // transient aliases inside agg_pk region (dead before first k_agg):
  float* cpo  = (float*)(R);                   // 10,240,000 B
  int* winner = (int*)(R + 10240000u);         // 320,000 B
  int* src_g  = (int*)(R + 10560000u);         // 2,420,000 B
  int* dst_g  = (int*)(R + 12980000u);         // 2,420,000 B
  u32* Xp_occ = (u32*)(R + 16000000u);         // 30,720,000 B
  u32* Xp_ch  = (u32*)(R + 46720000u);         // 2,560,000 B
  u32* Xp_se  = (u32*)(R + 49280000u);         // 640,000 B
  u32* Xp_nt  = (u32*)(R + 49920000u);         // 64,000 B
  u32* Xp_sd  = (u32*)(R + 49984000u);         // 6,400 B

  hipMemsetAsync(winner, 0xFF, kNo * 4, stream);
  hipMemsetAsync(cpo, 0, (size_t)kNo * 32 * 4, stream);
  hipMemsetAsync(cnt, 0, kN * 4, stream);

  // layer + classifier weight splits
  k_split<<<768, 256, 0, stream>>>(Wl, Wl_hi, Wl_lo, 3 * kH * kH);
  k_split<<<768, 256, 0, stream>>>(Wr, Wr_hi, Wr_lo, 3 * kH * kH);
  k_split<<<1024, 256, 0, stream>>>(Wc, Wc_hi, Wc_lo, kC * kH);

  // proj weight split + pad
  k_wsplit<<<(256 * 96 + 255) / 256, 256, 0, stream>>>(W_occ, 96, 96, Wo_hi, Wo_lo);
  k_wsplit<<<32, 256, 0, stream>>>(W_chord, 32, 32, Wch_hi, Wch_lo);
  k_wsplit<<<32, 256, 0, stream>>>(W_sec, 16, 32, Wse_hi, Wse_lo);
  k_wsplit<<<32, 256, 0, stream>>>(W_note, 16, 32, Wnt_hi, Wnt_lo);
  k_wsplit<<<32, 256, 0, stream>>>(W_sd, 8, 32, Wsd_hi, Wsd_lo);

  // chord -> occ feature scatter (numpy last-writer-wins)
  k_winner<<<(kNo + 255) / 256, 256, 0, stream>>>(ei[2], winner);
  k_scat<<<(kNo * 8) / 256, 256, 0, stream>>>(ei[2], winner, x_chord, cpo);

  // pack inputs (occ after cpo ready)
  k_pack2<<<(kNo * 96 + 255) / 256, 256, 0, stream>>>(x_occ, 64, cpo, 32, 96, Xp_occ, kNo);
  k_pack2<<<(kNc * 32 + 255) / 256, 256, 0, stream>>>(x_chord, 32, nullptr, 0, 32, Xp_ch, kNc);
  k_pack2<<<(kNs * 32 + 255) / 256, 256, 0, stream>>>(x_sec, 16, nullptr, 0, 32, Xp_se, kNs);
  k_pack2<<<(kNn * 32 + 255) / 256, 256, 0, stream>>>(x_note, 16, nullptr, 0, 32, Xp_nt, kNn);
  k_pack2<<<(kNd * 32 + 255) / 256, 256, 0, stream>>>(x_sd, 8, nullptr, 0, 32, Xp_sd, kNd);

  // MFMA projections -> h_pk
  {
    PArgs p{};
    p.Xp = Xp_occ; p.Wh = Wo_hi; p.Wlo = Wo_lo; p.bias = b_occ;
    p.emb = type_emb + 0 * kH; p.out = h_pk; p.M = kNo; p.Kp = 96;
    k_pmg<<<(kNo + 63) / 64, 256, 0, stream>>>(p);
    p.Xp = Xp_ch; p.Wh = Wch_hi; p.Wlo = Wch_lo; p.bias = b_chord;
    p.emb = type_emb + 1 * kH; p.out = h_pk + (size_t)kNo * kH; p.M = kNc; p.Kp = 32;
    k_pmg<<<(kNc + 63) / 64, 256, 0, stream>>>(p);
    p.Xp = Xp_se; p.Wh = Wse_hi; p.Wlo = Wse_lo; p.bias = b_sec;
    p.emb = type_emb + 2 * kH; p.out = h_pk + (size_t)100000 * kH; p.M = kNs; p.Kp = 32;
    k_pmg<<<(kNs + 63) / 64, 256, 0, stream>>>(p);
    p.Xp = Xp_nt; p.Wh = Wnt_hi; p.Wlo = Wnt_lo; p.bias = b_note;
    p.emb = type_emb + 3 * kH; p.out = h_pk + (size_t)105000 * kH; p.M = kNn; p.Kp = 32;
    k_pmg<<<(kNn + 63) / 64, 256, 0, stream>>>(p);
    p.Xp = Xp_sd; p.Wh = Wsd_hi; p.Wlo = Wsd_lo; p.bias = b_sd;
    p.emb = type_emb + 4 * kH; p.out = h_pk + (size_t)105500 * kH; p.M = kNd; p.Kp = 32;
    k_pmg<<<(kNd + 63) / 64, 256, 0, stream>>>(p);
  }

  // homogeneous edge list + CSR
  EdgeTab tab;
  const int ns_[10]  = {80000, 80000, 80000, 80000, 80000, 5000, 80000, 80000, 20000, 20000};
  const int sos_[10] = {0, 0, 80000, 0, 100000, 100000, 80000, 105000, 80000, 105500};
  const int dos_[10] = {0, 80000, 0, 100000, 0, 100000, 105000, 80000, 105500, 80000};
  int cum = 0;
  for (int i = 0; i < 10; ++i) {
    tab.p[i] = ei[i]; tab.n[i] = ns_[i]; tab.so[i] = sos_[i]; tab.dofs[i] = dos_[i];
    tab.cum[i] = cum; cum += ns_[i];
  }
  tab.cum[10] = cum;

  k_edges<<<(kE + 255) / 256, 256, 0, stream>>>(tab, src_g, dst_g, cnt);
  k_scan1<<<NBLK, 256, 0, stream>>>(cnt, bsum);
  k_scan2<<<1, 512, 0, stream>>>(bsum, bscan);
  k_scan3<<<NBLK, 256, 0, stream>>>(cnt, bscan, rowptr, cursor, inv);
  k_fill<<<(kE + 255) / 256, 256, 0, stream>>>(src_g, dst_g, cursor, csr_src);

  // 3 SAGE layers
  for (int l = 0; l < 3; ++l) {
    k_agg<<<(kN + 3) / 4, 256, 0, stream>>>(h_pk, rowptr, csr_src, inv, agg_pk);
    GArgs a{};
    const size_t off = (size_t)l * kH * kH;
    a.A[0] = agg_pk;      a.A[1] = h_pk;
    a.Wh[0] = Wl_hi + off; a.Wh[1] = Wr_hi + off;
    a.Wl[0] = Wl_lo + off; a.Wl[1] = Wr_lo + off;
    a.bias = bl + l * kH;
    a.lng = ln_g + l * kH;
    a.lnb = ln_b + l * kH;
    a.rpk = h_pk;
    a.outf = nullptr;
    a.opk = h_pk;
    a.M = kN; a.npass = 2; a.ostride = kH;
    k_mg<true><<<dim3((kN + 63) / 64, 1), 256, 0, stream>>>(a);
  }

  // classifier head over occ nodes (1-D grid, XCD-bijective + col-inner)
  GArgs c{};
  c.A[0] = h_pk;
  c.Wh[0] = Wc_hi;
  c.Wl[0] = Wc_lo;
  c.bias = bc;
  c.rpk = nullptr;
  c.outf = (float*)d_out;
  c.opk = nullptr;
  c.M = kNo; c.npass = 1; c.ostride = kC;
  k_mg<false><<<(kNo / 64) * 4, 256, 0, stream>>>(c);
}